// Round 7
// baseline (258.640 us; speedup 1.0000x reference)
//
#include <hip/hip_runtime.h>
#include <hip/hip_bf16.h>

// Attention_4363686773373: sigmoid attention block, all-bf16 MFMA pipeline.
// B=4 T=2048 D=768 H=12 HD=64.  Output fp32.
// R7: attn is LDS-BW-bound (K/V frag reads dominate). 256 thr / 4 waves x
// 32 q-rows (halves K/V LDS reads per pair: 22->14 B), double-buffer K/V
// with s-loop unrolled x2 so buffer bases are compile-time (static LDS
// offsets, 1 barrier/tile). GEMMs/prep unchanged from R5.

typedef __bf16 bf16_t;
typedef __bf16 bf16x8 __attribute__((ext_vector_type(8)));
typedef __bf16 bf16x4 __attribute__((ext_vector_type(4)));
typedef float floatx4 __attribute__((ext_vector_type(4)));

#define MFMA16x16x32(a, b, c) __builtin_amdgcn_mfma_f32_16x16x32_bf16((a), (b), (c), 0, 0, 0)

static constexpr float kEPS  = 1e-4f;
static constexpr float kGAIN = 1.8402f;
static constexpr float kC    = -0.18033688011112042f;   // -0.125 * log2(e)

// ---------------------------------------------------------------------------
// 1) merged preprocessing:
//    blocks [0,3072): row-normalize [qkv_w ; out_w] rows -> bf16
//    blocks [3072,11264): x -> bf16 + per-token magnitude ||x||/sqrt(D)
// ---------------------------------------------------------------------------
__global__ __launch_bounds__(256) void prep_kernel(const float* __restrict__ x,
                                                   const float* __restrict__ qkv_w,
                                                   const float* __restrict__ out_w,
                                                   bf16_t* __restrict__ wn_all,
                                                   bf16_t* __restrict__ xb,
                                                   float* __restrict__ mag) {
    __shared__ float red[4];
    int b = blockIdx.x;
    if (b < 3072) {
        const float* wr = (b < 2304) ? qkv_w + (size_t)b * 768
                                     : out_w + (size_t)(b - 2304) * 768;
        float ss = 0.f;
        for (int c = threadIdx.x; c < 768; c += 256) { float v = wr[c]; ss += v * v; }
        for (int m = 32; m; m >>= 1) ss += __shfl_xor(ss, m, 64);
        if ((threadIdx.x & 63) == 0) red[threadIdx.x >> 6] = ss;
        __syncthreads();
        float inv = 1.0f / (sqrtf(red[0] + red[1] + red[2] + red[3]) + kEPS);
        bf16_t* wo = wn_all + (size_t)b * 768;
        for (int c = threadIdx.x; c < 768; c += 256) wo[c] = (bf16_t)(wr[c] * inv);
    } else {
        int tok = b - 3072;               // 0..8191
        const float* xr = x + (size_t)tok * 768;
        float ss = 0.f;
        for (int c = threadIdx.x; c < 768; c += 256) { float v = xr[c]; ss += v * v; }
        for (int m = 32; m; m >>= 1) ss += __shfl_xor(ss, m, 64);
        if ((threadIdx.x & 63) == 0) red[threadIdx.x >> 6] = ss;
        __syncthreads();
        float tot = red[0] + red[1] + red[2] + red[3];
        if (threadIdx.x == 0) mag[tok] = sqrtf(tot) * 0.036084391824352f;  // 1/sqrt(768)
        bf16_t* xo = xb + (size_t)tok * 768;
        for (int c = threadIdx.x; c < 768; c += 256) xo[c] = (bf16_t)xr[c];
    }
}

// ---------------------------------------------------------------------------
// 3) GEMM1: qkv = xb(8192x768) @ wn^T(2304x768).  128x128 tile, BK=32,
//    register-prefetch pipeline. Lane-order LDS (stores lane-consecutive 16B).
//    Epilogue: q/k per-head normalize (q also *kC) -> qkvh; v (p==2)
//    transposed via LDS straight to vT (pi-permuted columns).
// ---------------------------------------------------------------------------
__global__ __launch_bounds__(256) void gemm_qkv_kernel(const bf16_t* __restrict__ A,
                                                       const bf16_t* __restrict__ Bw,
                                                       bf16_t* __restrict__ qkvh,
                                                       bf16_t* __restrict__ vT) {
    __shared__ __align__(16) bf16_t sm[8704];   // As 4096 | Bs 4096; reused 64x136 for v-transpose
    bf16_t* As = sm;
    bf16_t* Bs = sm + 4096;

    const int m0 = blockIdx.x * 128;
    const int n0 = blockIdx.y * 128;
    const int tid = threadIdx.x;
    const int wave = tid >> 6, lane = tid & 63;
    const int quad = lane >> 4, l16 = lane & 15;
    const int wr = (wave >> 1) * 64, wc = (wave & 1) * 64;
    const int srow = lane & 15, schunk = lane >> 4;   // staging lane map

    floatx4 acc[4][4];
    for (int i = 0; i < 4; i++)
        for (int j = 0; j < 4; j++) acc[i][j] = (floatx4){0.f, 0.f, 0.f, 0.f};

    const bf16_t* aptr0 = A  + (size_t)(m0 + wave * 32 + srow) * 768 + schunk * 8;
    const bf16_t* bptr0 = Bw + (size_t)(n0 + wave * 32 + srow) * 768 + schunk * 8;
    const int abase = wave * 1024;                    // per-wave region: 2 x 512

    uint4 ar0, ar1, br0, br1;
    auto issue = [&](int k0) {
        ar0 = *(const uint4*)(aptr0 + k0);
        ar1 = *(const uint4*)(aptr0 + k0 + 16 * 768);
        br0 = *(const uint4*)(bptr0 + k0);
        br1 = *(const uint4*)(bptr0 + k0 + 16 * 768);
    };
    issue(0);

    for (int it = 0; it < 24; ++it) {
        __syncthreads();                 // prev tile's frag reads done
        *(uint4*)&As[abase + lane * 8]       = ar0;
        *(uint4*)&As[abase + 512 + lane * 8] = ar1;
        *(uint4*)&Bs[abase + lane * 8]       = br0;
        *(uint4*)&Bs[abase + 512 + lane * 8] = br1;
        if (it < 23) issue((it + 1) * 32);   // prefetch hides under compute
        __syncthreads();                 // tile visible

        bf16x8 af[4], bfr[4];
#pragma unroll
        for (int i = 0; i < 4; i++)
            af[i] = *(const bf16x8*)&As[((wr >> 4) + i) * 512 + quad * 128 + l16 * 8];
#pragma unroll
        for (int j = 0; j < 4; j++)
            bfr[j] = *(const bf16x8*)&Bs[((wc >> 4) + j) * 512 + quad * 128 + l16 * 8];
#pragma unroll
        for (int i = 0; i < 4; i++)
#pragma unroll
            for (int j = 0; j < 4; j++) acc[i][j] = MFMA16x16x32(af[i], bfr[j], acc[i][j]);
    }

    const int p = n0 / 768;        // block-uniform (768 % 128 == 0)
    const int bat = m0 >> 11, t0 = m0 & 2047;

    if (p < 2) {
        // ---- q/k: fused per-head normalize, scatter to qkvh ----
        const int h = ((n0 + wc) - p * 768) >> 6;
        const float base = (p == 0) ? kC * 8.0f : 8.0f;
        for (int i = 0; i < 4; i++)
            for (int r = 0; r < 4; r++) {
                float vals[4], ss = 0.f;
                for (int j = 0; j < 4; j++) { float v = acc[i][j][r]; vals[j] = v; ss += v * v; }
                ss += __shfl_xor(ss, 1, 64);
                ss += __shfl_xor(ss, 2, 64);
                ss += __shfl_xor(ss, 4, 64);
                ss += __shfl_xor(ss, 8, 64);
                float scale = base / (sqrtf(ss) + kEPS);
                int m = m0 + wr + i * 16 + quad * 4 + r;
                int t = m & 2047;
                bf16_t* dst = qkvh + ((((size_t)p * 4 + bat) * 12 + h) * 2048 + t) * 64;
                for (int j = 0; j < 4; j++) dst[j * 16 + l16] = (bf16_t)(vals[j] * scale);
            }
    } else {
        // ---- v: transpose via LDS, write vT[(bh)*64+d][t] pi-permuted ----
        __syncthreads();                         // everyone done with As/Bs
        const int h0 = (n0 - 1536) >> 6;         // block head base (2 heads/block)
        for (int hh = 0; hh < 2; hh++) {
            if ((wc >> 6) == hh) {
                for (int i = 0; i < 4; i++)
                    for (int r = 0; r < 4; r++) {
                        int tl = wr + i * 16 + quad * 4 + r;
                        for (int j = 0; j < 4; j++)
                            sm[(j * 16 + l16) * 136 + tl] = (bf16_t)acc[i][j][r];
                    }
            }
            __syncthreads();
            bf16_t* dst = vT + ((size_t)(bat * 12 + h0 + hh) * 64) * 2048 + t0;
            for (int u = tid; u < 1024; u += 256) {
                int d = u >> 4, c = u & 15;
                bf16_t tmp[8];
#pragma unroll
                for (int q = 0; q < 8; q++) {
                    int sp = c * 8 + q;                      // out position 0..127
                    int q6 = sp & 63;
                    int tl = (sp & 64) + ((q6 & 3) << 4) + (q6 >> 2);   // pi_inv
                    tmp[q] = sm[d * 136 + tl];
                }
                *(uint4*)&dst[(size_t)d * 2048 + c * 8] = *(uint4*)tmp;
            }
            __syncthreads();
        }
    }
}

// ---------------------------------------------------------------------------
// 6) sigmoid attention, fused per-head output normalize + mag rescale.
//    grid (48, 16): x = head (XCD-affine), y = q-tile. R7: 256 thr = 4 waves
//    x 32 q-rows (2x K/V frag reuse), s-tile 64, dbuf K/V with s-loop
//    unrolled x2 (compile-time buffer bases -> static LDS offsets), one
//    barrier per tile. LDS 48KB -> 3 blocks/CU (= grid 768 / 256 CU).
// ---------------------------------------------------------------------------
__global__ __launch_bounds__(256) void attn_kernel(const bf16_t* __restrict__ qkvh,
                                                   const bf16_t* __restrict__ vT,
                                                   const float* __restrict__ mag,
                                                   bf16_t* __restrict__ y) {
    __shared__ bf16_t QP[128 * 64];          // Q tile, then reused as Ps
    __shared__ bf16_t KV[2][2][64 * 64];     // [buf][0=K,1=V(pi-order)]

    const int bh = blockIdx.x, bat = bh / 12, h = bh % 12;
    const int m0 = blockIdx.y * 128;
    const bf16_t* qbase = qkvh + (((size_t)bat * 12 + h) * 2048) * 64;            // p=0
    const bf16_t* kbase = qkvh + (((size_t)(4 + bat) * 12 + h) * 2048) * 64;      // p=1
    const bf16_t* vbase = vT + ((size_t)bh * 64) * 2048;

    const int tid = threadIdx.x, wave = tid >> 6, lane = tid & 63;
    const int quad = lane >> 4, l16 = lane & 15;

    // ---- stage Q (swizzled): 1024 uint4 over 256 threads ----
    for (int s = tid; s < 1024; s += 256) {
        int r = s >> 3, blk = s & 7;
        *(uint4*)&QP[r * 64 + ((blk ^ (r & 7)) * 8)] =
            *(const uint4*)&qbase[(size_t)(m0 + r) * 64 + blk * 8];
    }

    // ---- K/V prefetch (2 uint4 of each per thread) ----
    uint4 kr0, kr1, vr0, vr1;
    const int slr = tid >> 3, slb = tid & 7;          // slr 0..31
    auto issue = [&](int s0) {
        kr0 = *(const uint4*)&kbase[(size_t)(s0 + slr) * 64 + slb * 8];
        kr1 = *(const uint4*)&kbase[(size_t)(s0 + slr + 32) * 64 + slb * 8];
        vr0 = *(const uint4*)&vbase[(size_t)slr * 2048 + s0 + slb * 8];
        vr1 = *(const uint4*)&vbase[(size_t)(slr + 32) * 2048 + s0 + slb * 8];
    };
    const int sw = ((slb ^ (slr & 7)) * 8);           // (slr+32)&7 == slr&7

    issue(0);
    __syncthreads();   // Q staged

    // ---- Q fragments -> registers (wave-private rows; QP freed for Ps) ----
    bf16x8 qf[2][2];
#pragma unroll
    for (int i = 0; i < 2; i++) {
        int row = wave * 32 + i * 16 + l16;
        qf[i][0] = *(const bf16x8*)&QP[row * 64 + ((quad ^ (l16 & 7)) * 8)];
        qf[i][1] = *(const bf16x8*)&QP[row * 64 + (((4 + quad) ^ (l16 & 7)) * 8)];
    }

    // commit tile 0 into buf 0, prefetch tile 1
    *(uint4*)&KV[0][0][slr * 64 + sw]        = kr0;
    *(uint4*)&KV[0][0][(slr + 32) * 64 + sw] = kr1;
    *(uint4*)&KV[0][1][slr * 64 + sw]        = vr0;
    *(uint4*)&KV[0][1][(slr + 32) * 64 + sw] = vr1;
    issue(64);
    __syncthreads();   // KV[0] visible; all qf reads done before Ps writes

    const int boff0 = ((quad ^ (l16 & 7)) * 8);
    const int boff1 = (((4 + quad) ^ (l16 & 7)) * 8);

    floatx4 o[2][4];
#pragma unroll
    for (int i = 0; i < 2; i++)
#pragma unroll
        for (int j = 0; j < 4; j++) o[i][j] = (floatx4){0.f, 0.f, 0.f, 0.f};

    // one s-tile step; BUF is a compile-time constant -> static LDS bases
#define ATTN_STEP(BUF, IT)                                                        \
    {                                                                             \
        if ((IT) < 31) {                                                          \
            *(uint4*)&KV[1 - (BUF)][0][slr * 64 + sw]        = kr0;               \
            *(uint4*)&KV[1 - (BUF)][0][(slr + 32) * 64 + sw] = kr1;               \
            *(uint4*)&KV[1 - (BUF)][1][slr * 64 + sw]        = vr0;               \
            *(uint4*)&KV[1 - (BUF)][1][(slr + 32) * 64 + sw] = vr1;               \
            if ((IT) < 30) issue(((IT) + 2) * 64);                                \
        }                                                                         \
        const bf16_t* const Ks = KV[BUF][0];                                      \
        const bf16_t* const Vt = KV[BUF][1];                                      \
        floatx4 sacc[2][4];                                                       \
        _Pragma("unroll")                                                         \
        for (int i = 0; i < 2; i++)                                               \
            _Pragma("unroll")                                                     \
            for (int j = 0; j < 4; j++) sacc[i][j] = (floatx4){0.f, 0.f, 0.f, 0.f}; \
        _Pragma("unroll")                                                         \
        for (int j = 0; j < 4; j++) {                                             \
            bf16x8 b0 = *(const bf16x8*)&Ks[(j * 16 + l16) * 64 + boff0];         \
            bf16x8 b1 = *(const bf16x8*)&Ks[(j * 16 + l16) * 64 + boff1];         \
            _Pragma("unroll")                                                     \
            for (int i = 0; i < 2; i++) {                                         \
                sacc[i][j] = MFMA16x16x32(qf[i][0], b0, sacc[i][j]);              \
                sacc[i][j] = MFMA16x16x32(qf[i][1], b1, sacc[i][j]);              \
            }                                                                     \
        }                                                                         \
        _Pragma("unroll")                                                         \
        for (int i = 0; i < 2; i++)                                               \
            _Pragma("unroll")                                                     \
            for (int r = 0; r < 4; r++) {                                         \
                int row = wave * 32 + i * 16 + quad * 4 + r;                      \
                bf16x4 pk;                                                        \
                _Pragma("unroll")                                                 \
                for (int j = 0; j < 4; j++) {                                     \
                    float t = __builtin_amdgcn_exp2f(sacc[i][j][r]);              \
                    pk[j] = (bf16_t)__builtin_amdgcn_rcpf(1.0f + t);              \
                }                                                                 \
                *(bf16x4*)&QP[row * 64 + (((l16 >> 1) ^ (row & 7)) * 8) +         \
                              (l16 & 1) * 4] = pk;                                \
            }                                                                     \
        _Pragma("unroll")                                                         \
        for (int i = 0; i < 2; i++) {                                             \
            int prow = wave * 32 + i * 16 + l16;                                  \
            bf16x8 af0 = *(const bf16x8*)&QP[prow * 64 + boff0];                  \
            bf16x8 af1 = *(const bf16x8*)&QP[prow * 64 + boff1];                  \
            _Pragma("unroll")                                                     \
            for (int j = 0; j < 4; j++) {                                         \
                bf16x8 b0 = *(const bf16x8*)&Vt[(j * 16 + l16) * 64 + boff0];     \
                bf16x8 b1 = *(const bf16x8*)&Vt[(j * 16 + l16) * 64 + boff1];     \
                o[i][j] = MFMA16x16x32(af0, b0, o[i][j]);                         \
                o[i][j] = MFMA16x16x32(af1, b1, o[i][j]);                         \
            }                                                                     \
        }                                                                         \
        __syncthreads();                                                          \
    }

    for (int it = 0; it < 32; it += 2) {
        ATTN_STEP(0, it)
        ATTN_STEP(1, it + 1)
    }
#undef ATTN_STEP

    // ---- epilogue: out = mag * 8 * (kGAIN/sqrt(T)) * o / (||...|| + eps) ----
    const float kfac = kGAIN * 0.02209708691207961f;  // 1.8402/sqrt(2048)
#pragma unroll
    for (int i = 0; i < 2; i++)
#pragma unroll
        for (int r = 0; r < 4; r++) {
            int t = m0 + wave * 32 + i * 16 + quad * 4 + r;
            float vals[4];
            float ss = 0.f;
#pragma unroll
            for (int j = 0; j < 4; j++) {
                float v = o[i][j][r] * kfac;
                vals[j] = v;
                ss += v * v;
            }
            for (int msk = 1; msk < 16; msk <<= 1) ss += __shfl_xor(ss, msk, 64);
            float mg = mag[bat * 2048 + t];
            float sc = mg * 8.0f / (sqrtf(ss) + kEPS);
#pragma unroll
            for (int j = 0; j < 4; j++) {
                int d = j * 16 + l16;
                y[((size_t)(bat * 2048 + t)) * 768 + h * 64 + d] = (bf16_t)(vals[j] * sc);
            }
        }
}

// ---------------------------------------------------------------------------
// 7) GEMM2: out = y(8192x768) @ ow^T(768x768) -> fp32, BK=32, reg-prefetch
// ---------------------------------------------------------------------------
__global__ __launch_bounds__(256) void gemm_out_kernel(const bf16_t* __restrict__ A,
                                                       const bf16_t* __restrict__ Bw,
                                                       float* __restrict__ out) {
    __shared__ __align__(16) bf16_t sm[8192];
    bf16_t* As = sm;
    bf16_t* Bs = sm + 4096;

    const int m0 = blockIdx.x * 128;
    const int n0 = blockIdx.y * 128;
    const int tid = threadIdx.x;
    const int wave = tid >> 6, lane = tid & 63;
    const int quad = lane >> 4, l16 = lane & 15;
    const int wr = (wave >> 1) * 64, wc = (wave & 1) * 64;
    const int srow = lane & 15, schunk = lane >> 4;

    floatx4 acc[4][4];
    for (int i = 0; i < 4; i++)
        for (int j = 0; j < 4; j++) acc[i][j] = (floatx4){0.f, 0.f, 0.f, 0.f};

    const bf16_t* aptr0 = A  + (size_t)(m0 + wave * 32 + srow) * 768 + schunk * 8;
    const bf16_t* bptr0 = Bw + (size_t)(n0 + wave * 32 + srow) * 768 + schunk * 8;
    const int abase = wave * 1024;

    uint4 ar0, ar1, br0, br1;
    auto issue = [&](int k0) {
        ar0 = *(const uint4*)(aptr0 + k0);
        ar1 = *(const uint4*)(aptr0 + k0 + 16 * 768);
        br0 = *(const uint4*)(bptr0 + k0);
        br1 = *(const uint4*)(bptr0 + k0 + 16 * 768);
    };
    issue(0);

    for (int it = 0; it < 24; ++it) {
        __syncthreads();
        *(uint4*)&As[abase + lane * 8]       = ar0;
        *(uint4*)&As[abase + 512 + lane * 8] = ar1;
        *(uint4*)&Bs[abase + lane * 8]       = br0;
        *(uint4*)&Bs[abase + 512 + lane * 8] = br1;
        if (it < 23) issue((it + 1) * 32);
        __syncthreads();

        bf16x8 af[4], bfr[4];
#pragma unroll
        for (int i = 0; i < 4; i++)
            af[i] = *(const bf16x8*)&As[((wr >> 4) + i) * 512 + quad * 128 + l16 * 8];
#pragma unroll
        for (int j = 0; j < 4; j++)
            bfr[j] = *(const bf16x8*)&Bs[((wc >> 4) + j) * 512 + quad * 128 + l16 * 8];
#pragma unroll
        for (int i = 0; i < 4; i++)
#pragma unroll
            for (int j = 0; j < 4; j++) acc[i][j] = MFMA16x16x32(af[i], bfr[j], acc[i][j]);
    }
    for (int i = 0; i < 4; i++)
        for (int j = 0; j < 4; j++) {
            int n = n0 + wc + j * 16 + l16;
            for (int r = 0; r < 4; r++) {
                int m = m0 + wr + i * 16 + quad * 4 + r;
                out[(size_t)m * 768 + n] = acc[i][j][r];
            }
        }
}

// ---------------------------------------------------------------------------
extern "C" void kernel_launch(void* const* d_in, const int* in_sizes, int n_in,
                              void* d_out, int out_size, void* d_ws, size_t ws_size,
                              hipStream_t stream) {
    const float* x     = (const float*)d_in[0];   // (4,2048,768)
    const float* qkv_w = (const float*)d_in[1];   // (2304,768)
    const float* out_w = (const float*)d_in[2];   // (768,768)
    float* out = (float*)d_out;

    char* ws = (char*)d_ws;
    bf16_t* wn_all = (bf16_t*)(ws + 0);          //  4,718,592  (3072x768 bf16: qkv_w rows then out_w rows)
    bf16_t* xb     = (bf16_t*)(ws + 4718592);    // 12,582,912  (8192x768 bf16)
    float*  mag    = (float*) (ws + 17301504);   //     32,768  (8192 fp32)
    bf16_t* qkvh   = (bf16_t*)(ws + 17334272);   // 25,165,824  (2x4x12x2048x64 bf16: q,k)
    bf16_t* vT     = (bf16_t*)(ws + 42500096);   // 12,582,912  (48x64x2048 bf16, pi-permuted cols)
    bf16_t* y      = (bf16_t*)(ws + 55083008);   // 12,582,912  (8192x768 bf16)
    // total 67,665,920 bytes

    bf16_t* ow = wn_all + (size_t)2304 * 768;

    prep_kernel<<<11264, 256, 0, stream>>>(x, qkv_w, out_w, wn_all, xb, mag);
    gemm_qkv_kernel<<<dim3(64, 18), 256, 0, stream>>>(xb, wn_all, qkvh, vT);
    attn_kernel<<<dim3(48, 16), 256, 0, stream>>>(qkvh, vT, mag, y);
    gemm_out_kernel<<<dim3(64, 6), 256, 0, stream>>>(y, ow, out);
}

// Round 8
// 248.123 us; speedup vs baseline: 1.0424x; 1.0424x over previous
//
#include <hip/hip_runtime.h>
#include <hip/hip_bf16.h>

// Attention_4363686773373: sigmoid attention block, all-bf16 MFMA pipeline.
// B=4 T=2048 D=768 H=12 HD=64.  Output fp32.
// R8: attn -> s-partitioned waves (4 m-groups x 2 s-groups), S^T = K.Q^T so
// each K/V tile is read by 4 waves not 8 (LDS/iter 176->112KB). P^T wave-
// private in QP (plain pack, no pi permutation -> vT is a plain transpose).
// PV as O^T = V^T.P; cross-sg O reduction via LDS at end. R5 pipeline kept.

typedef __bf16 bf16_t;
typedef __bf16 bf16x8 __attribute__((ext_vector_type(8)));
typedef __bf16 bf16x4 __attribute__((ext_vector_type(4)));
typedef float floatx4 __attribute__((ext_vector_type(4)));

#define MFMA16x16x32(a, b, c) __builtin_amdgcn_mfma_f32_16x16x32_bf16((a), (b), (c), 0, 0, 0)

static constexpr float kEPS  = 1e-4f;
static constexpr float kGAIN = 1.8402f;
static constexpr float kC    = -0.18033688011112042f;   // -0.125 * log2(e)

// ---------------------------------------------------------------------------
// 1) merged preprocessing:
//    blocks [0,3072): row-normalize [qkv_w ; out_w] rows -> bf16
//    blocks [3072,11264): x -> bf16 + per-token magnitude ||x||/sqrt(D)
// ---------------------------------------------------------------------------
__global__ __launch_bounds__(256) void prep_kernel(const float* __restrict__ x,
                                                   const float* __restrict__ qkv_w,
                                                   const float* __restrict__ out_w,
                                                   bf16_t* __restrict__ wn_all,
                                                   bf16_t* __restrict__ xb,
                                                   float* __restrict__ mag) {
    __shared__ float red[4];
    int b = blockIdx.x;
    if (b < 3072) {
        const float* wr = (b < 2304) ? qkv_w + (size_t)b * 768
                                     : out_w + (size_t)(b - 2304) * 768;
        float ss = 0.f;
        for (int c = threadIdx.x; c < 768; c += 256) { float v = wr[c]; ss += v * v; }
        for (int m = 32; m; m >>= 1) ss += __shfl_xor(ss, m, 64);
        if ((threadIdx.x & 63) == 0) red[threadIdx.x >> 6] = ss;
        __syncthreads();
        float inv = 1.0f / (sqrtf(red[0] + red[1] + red[2] + red[3]) + kEPS);
        bf16_t* wo = wn_all + (size_t)b * 768;
        for (int c = threadIdx.x; c < 768; c += 256) wo[c] = (bf16_t)(wr[c] * inv);
    } else {
        int tok = b - 3072;               // 0..8191
        const float* xr = x + (size_t)tok * 768;
        float ss = 0.f;
        for (int c = threadIdx.x; c < 768; c += 256) { float v = xr[c]; ss += v * v; }
        for (int m = 32; m; m >>= 1) ss += __shfl_xor(ss, m, 64);
        if ((threadIdx.x & 63) == 0) red[threadIdx.x >> 6] = ss;
        __syncthreads();
        float tot = red[0] + red[1] + red[2] + red[3];
        if (threadIdx.x == 0) mag[tok] = sqrtf(tot) * 0.036084391824352f;  // 1/sqrt(768)
        bf16_t* xo = xb + (size_t)tok * 768;
        for (int c = threadIdx.x; c < 768; c += 256) xo[c] = (bf16_t)xr[c];
    }
}

// ---------------------------------------------------------------------------
// 3) GEMM1: qkv = xb(8192x768) @ wn^T(2304x768).  128x128 tile, BK=32,
//    register-prefetch pipeline. Lane-order LDS (stores lane-consecutive 16B).
//    Epilogue: q/k per-head normalize (q also *kC) -> qkvh; v (p==2)
//    transposed via LDS straight to vT (PLAIN transpose, no pi permutation).
// ---------------------------------------------------------------------------
__global__ __launch_bounds__(256) void gemm_qkv_kernel(const bf16_t* __restrict__ A,
                                                       const bf16_t* __restrict__ Bw,
                                                       bf16_t* __restrict__ qkvh,
                                                       bf16_t* __restrict__ vT) {
    __shared__ __align__(16) bf16_t sm[8704];   // As 4096 | Bs 4096; reused 64x136 for v-transpose
    bf16_t* As = sm;
    bf16_t* Bs = sm + 4096;

    const int m0 = blockIdx.x * 128;
    const int n0 = blockIdx.y * 128;
    const int tid = threadIdx.x;
    const int wave = tid >> 6, lane = tid & 63;
    const int quad = lane >> 4, l16 = lane & 15;
    const int wr = (wave >> 1) * 64, wc = (wave & 1) * 64;
    const int srow = lane & 15, schunk = lane >> 4;   // staging lane map

    floatx4 acc[4][4];
    for (int i = 0; i < 4; i++)
        for (int j = 0; j < 4; j++) acc[i][j] = (floatx4){0.f, 0.f, 0.f, 0.f};

    const bf16_t* aptr0 = A  + (size_t)(m0 + wave * 32 + srow) * 768 + schunk * 8;
    const bf16_t* bptr0 = Bw + (size_t)(n0 + wave * 32 + srow) * 768 + schunk * 8;
    const int abase = wave * 1024;                    // per-wave region: 2 x 512

    uint4 ar0, ar1, br0, br1;
    auto issue = [&](int k0) {
        ar0 = *(const uint4*)(aptr0 + k0);
        ar1 = *(const uint4*)(aptr0 + k0 + 16 * 768);
        br0 = *(const uint4*)(bptr0 + k0);
        br1 = *(const uint4*)(bptr0 + k0 + 16 * 768);
    };
    issue(0);

    for (int it = 0; it < 24; ++it) {
        __syncthreads();                 // prev tile's frag reads done
        *(uint4*)&As[abase + lane * 8]       = ar0;
        *(uint4*)&As[abase + 512 + lane * 8] = ar1;
        *(uint4*)&Bs[abase + lane * 8]       = br0;
        *(uint4*)&Bs[abase + 512 + lane * 8] = br1;
        if (it < 23) issue((it + 1) * 32);   // prefetch hides under compute
        __syncthreads();                 // tile visible

        bf16x8 af[4], bfr[4];
#pragma unroll
        for (int i = 0; i < 4; i++)
            af[i] = *(const bf16x8*)&As[((wr >> 4) + i) * 512 + quad * 128 + l16 * 8];
#pragma unroll
        for (int j = 0; j < 4; j++)
            bfr[j] = *(const bf16x8*)&Bs[((wc >> 4) + j) * 512 + quad * 128 + l16 * 8];
#pragma unroll
        for (int i = 0; i < 4; i++)
#pragma unroll
            for (int j = 0; j < 4; j++) acc[i][j] = MFMA16x16x32(af[i], bfr[j], acc[i][j]);
    }

    const int p = n0 / 768;        // block-uniform (768 % 128 == 0)
    const int bat = m0 >> 11, t0 = m0 & 2047;

    if (p < 2) {
        // ---- q/k: fused per-head normalize, scatter to qkvh ----
        const int h = ((n0 + wc) - p * 768) >> 6;
        const float base = (p == 0) ? kC * 8.0f : 8.0f;
        for (int i = 0; i < 4; i++)
            for (int r = 0; r < 4; r++) {
                float vals[4], ss = 0.f;
                for (int j = 0; j < 4; j++) { float v = acc[i][j][r]; vals[j] = v; ss += v * v; }
                ss += __shfl_xor(ss, 1, 64);
                ss += __shfl_xor(ss, 2, 64);
                ss += __shfl_xor(ss, 4, 64);
                ss += __shfl_xor(ss, 8, 64);
                float scale = base / (sqrtf(ss) + kEPS);
                int m = m0 + wr + i * 16 + quad * 4 + r;
                int t = m & 2047;
                bf16_t* dst = qkvh + ((((size_t)p * 4 + bat) * 12 + h) * 2048 + t) * 64;
                for (int j = 0; j < 4; j++) dst[j * 16 + l16] = (bf16_t)(vals[j] * scale);
            }
    } else {
        // ---- v: transpose via LDS, write vT[(bh)*64+d][t] (plain) ----
        __syncthreads();                         // everyone done with As/Bs
        const int h0 = (n0 - 1536) >> 6;         // block head base (2 heads/block)
        for (int hh = 0; hh < 2; hh++) {
            if ((wc >> 6) == hh) {
                for (int i = 0; i < 4; i++)
                    for (int r = 0; r < 4; r++) {
                        int tl = wr + i * 16 + quad * 4 + r;
                        for (int j = 0; j < 4; j++)
                            sm[(j * 16 + l16) * 136 + tl] = (bf16_t)acc[i][j][r];
                    }
            }
            __syncthreads();
            bf16_t* dst = vT + ((size_t)(bat * 12 + h0 + hh) * 64) * 2048 + t0;
            for (int u = tid; u < 1024; u += 256) {
                int d = u >> 4, c = u & 15;
                *(uint4*)&dst[(size_t)d * 2048 + c * 8] =
                    *(const uint4*)&sm[d * 136 + c * 8];
            }
            __syncthreads();
        }
    }
}

// ---------------------------------------------------------------------------
// 6) sigmoid attention, fused per-head output normalize + mag rescale.
//    grid (48, 16): x = head (XCD-affine), y = q-tile. 512 thr = 8 waves =
//    4 m-groups x 2 s-groups. Wave (mg,sg) computes S^T = K.Q^T for its
//    32-s slice x 32 m (K/V amplification 4, was 8), P^T wave-private in QP,
//    PV as O^T = V^T.P, cross-sg O reduction at end. dbuf K/V, 1 barrier/iter.
// ---------------------------------------------------------------------------
__global__ __launch_bounds__(512, 4) void attn_kernel(const bf16_t* __restrict__ qkvh,
                                                      const bf16_t* __restrict__ vT,
                                                      const float* __restrict__ mag,
                                                      bf16_t* __restrict__ y) {
    __shared__ __align__(16) bf16_t smem[24576];   // 48KB: QP 16K | KV dbuf 32K
    bf16_t* const QP = smem;                       // Q stage, then P^T buffer

    const int bh = blockIdx.x, bat = bh / 12, h = bh % 12;
    const int m0 = blockIdx.y * 128;
    const bf16_t* qbase = qkvh + (((size_t)bat * 12 + h) * 2048) * 64;            // p=0
    const bf16_t* kbase = qkvh + (((size_t)(4 + bat) * 12 + h) * 2048) * 64;      // p=1
    const bf16_t* vbase = vT + ((size_t)bh * 64) * 2048;

    const int tid = threadIdx.x, wave = tid >> 6, lane = tid & 63;
    const int quad = (lane >> 4) & 3, l16 = lane & 15;
    const int mg = wave >> 1, sg = wave & 1;

    // ---- stage Q (swizzled): 1024 uint4 over 512 threads ----
    for (int s = tid; s < 1024; s += 512) {
        int r = s >> 3, blk = s & 7;
        *(uint4*)&QP[r * 64 + ((blk ^ (r & 7)) * 8)] =
            *(const uint4*)&qbase[(size_t)(m0 + r) * 64 + blk * 8];
    }

    // ---- K/V prefetch (1 uint4 of each per thread) ----
    uint4 kr, vr;
    const int slr = tid >> 3, slb = tid & 7;
    auto issue = [&](int s0) {
        kr = *(const uint4*)&kbase[(size_t)(s0 + slr) * 64 + slb * 8];
        vr = *(const uint4*)&vbase[(size_t)slr * 2048 + s0 + slb * 8];
    };
    const int sw = ((slb ^ (slr & 7)) * 8);
    auto commit = [&](int buf) {
        *(uint4*)&smem[8192 + buf * 8192 + slr * 64 + sw]        = kr;   // K
        *(uint4*)&smem[8192 + buf * 8192 + 4096 + slr * 64 + sw] = vr;   // V^T
    };

    issue(0);
    __syncthreads();   // Q staged

    // ---- Q B-frags -> regs (rows m = mg*32 + mi*16 + l16; QP freed for P^T)
    bf16x8 qfB[2][2];
#pragma unroll
    for (int mi = 0; mi < 2; mi++) {
        int row = mg * 32 + mi * 16 + l16;
        qfB[mi][0] = *(const bf16x8*)&QP[row * 64 + ((quad ^ (row & 7)) * 8)];
        qfB[mi][1] = *(const bf16x8*)&QP[row * 64 + (((4 + quad) ^ (row & 7)) * 8)];
    }

    commit(0);
    issue(64);
    __syncthreads();   // KV[0] visible; qfB reads done before any P^T write

    floatx4 Ot[4][2];   // O^T[d-tile][m-tile], partial over this wave's sg-half
#pragma unroll
    for (int dt = 0; dt < 4; dt++)
#pragma unroll
        for (int mi = 0; mi < 2; mi++) Ot[dt][mi] = (floatx4){0.f, 0.f, 0.f, 0.f};

    for (int it = 0; it < 32; ++it) {
        const bf16_t* Ks = &smem[8192 + (it & 1) * 8192];
        const bf16_t* Vt = Ks + 4096;
        if (it < 31) {
            commit((it + 1) & 1);        // regs loaded one iter ago
            if (it < 30) issue((it + 2) * 64);
        }

        // ---- S^T = K.Q^T : this wave's 32 s-rows x 32 m-cols ----
        floatx4 sacc[2][2];
#pragma unroll
        for (int si = 0; si < 2; si++)
#pragma unroll
            for (int mi = 0; mi < 2; mi++) sacc[si][mi] = (floatx4){0.f, 0.f, 0.f, 0.f};
#pragma unroll
        for (int si = 0; si < 2; si++) {
            int rk = sg * 32 + si * 16 + l16;
            bf16x8 a0 = *(const bf16x8*)&Ks[rk * 64 + ((quad ^ (rk & 7)) * 8)];
            bf16x8 a1 = *(const bf16x8*)&Ks[rk * 64 + (((4 + quad) ^ (rk & 7)) * 8)];
#pragma unroll
            for (int mi = 0; mi < 2; mi++) {
                sacc[si][mi] = MFMA16x16x32(a0, qfB[mi][0], sacc[si][mi]);
                sacc[si][mi] = MFMA16x16x32(a1, qfB[mi][1], sacc[si][mi]);
            }
        }

        // ---- sigmoid -> P^T[m][s] in QP (wave-private quadrant, plain order)
#pragma unroll
        for (int mi = 0; mi < 2; mi++) {
            int row = mg * 32 + mi * 16 + l16;
#pragma unroll
            for (int si = 0; si < 2; si++) {
                bf16x4 pk;
#pragma unroll
                for (int r = 0; r < 4; r++) {
                    float t = __builtin_amdgcn_exp2f(sacc[si][mi][r]);
                    pk[r] = (bf16_t)__builtin_amdgcn_rcpf(1.0f + t);
                }
                int chunk = sg * 4 + si * 2 + (quad >> 1);
                *(bf16x4*)&QP[row * 64 + ((chunk ^ (row & 7)) * 8) + (quad & 1) * 4] = pk;
            }
        }

        // ---- O^T += V^T.P  (A = V^T rows d, B = P^T rows m, k = s-slice) ----
        bf16x8 pf[2];
#pragma unroll
        for (int mi = 0; mi < 2; mi++) {
            int row = mg * 32 + mi * 16 + l16;
            pf[mi] = *(const bf16x8*)&QP[row * 64 + (((sg * 4 + quad) ^ (row & 7)) * 8)];
        }
#pragma unroll
        for (int dt = 0; dt < 4; dt++) {
            int rd = dt * 16 + l16;
            bf16x8 vf = *(const bf16x8*)&Vt[rd * 64 + (((sg * 4 + quad) ^ (rd & 7)) * 8)];
#pragma unroll
            for (int mi = 0; mi < 2; mi++)
                Ot[dt][mi] = MFMA16x16x32(vf, pf[mi], Ot[dt][mi]);
        }
        __syncthreads();   // one barrier per s-tile
    }

    // ---- cross-sg reduction + fused normalize/mag epilogue ----
    float* scr = (float*)smem;                 // [mg][m 32][d 64 (+4 pad)] fp32
    if (sg == 1) {
#pragma unroll
        for (int mi = 0; mi < 2; mi++)
#pragma unroll
            for (int dt = 0; dt < 4; dt++)
                *(floatx4*)&scr[mg * 2176 + (mi * 16 + l16) * 68 + dt * 16 + quad * 4] =
                    Ot[dt][mi];
    }
    __syncthreads();
    if (sg == 0) {
        const float kfac = kGAIN * 0.02209708691207961f;  // 1.8402/sqrt(2048)
#pragma unroll
        for (int mi = 0; mi < 2; mi++) {
            float vals[4][4];
            float ss = 0.f;
#pragma unroll
            for (int dt = 0; dt < 4; dt++) {
                floatx4 part = *(const floatx4*)
                    &scr[mg * 2176 + (mi * 16 + l16) * 68 + dt * 16 + quad * 4];
#pragma unroll
                for (int r = 0; r < 4; r++) {
                    float v = (Ot[dt][mi][r] + part[r]) * kfac;
                    vals[dt][r] = v;
                    ss += v * v;
                }
            }
            ss += __shfl_xor(ss, 16, 64);   // sum over quads (same l16)
            ss += __shfl_xor(ss, 32, 64);
            int t = m0 + mg * 32 + mi * 16 + l16;
            float mgv = mag[bat * 2048 + t];
            float sc = mgv * 8.0f / (sqrtf(ss) + kEPS);
            bf16_t* yp = y + ((size_t)(bat * 2048 + t)) * 768 + h * 64;
#pragma unroll
            for (int dt = 0; dt < 4; dt++) {
                bf16x4 ov;
#pragma unroll
                for (int r = 0; r < 4; r++) ov[r] = (bf16_t)(vals[dt][r] * sc);
                *(bf16x4*)&yp[dt * 16 + quad * 4] = ov;
            }
        }
    }
}

// ---------------------------------------------------------------------------
// 7) GEMM2: out = y(8192x768) @ ow^T(768x768) -> fp32, BK=32, reg-prefetch
// ---------------------------------------------------------------------------
__global__ __launch_bounds__(256) void gemm_out_kernel(const bf16_t* __restrict__ A,
                                                       const bf16_t* __restrict__ Bw,
                                                       float* __restrict__ out) {
    __shared__ __align__(16) bf16_t sm[8192];
    bf16_t* As = sm;
    bf16_t* Bs = sm + 4096;

    const int m0 = blockIdx.x * 128;
    const int n0 = blockIdx.y * 128;
    const int tid = threadIdx.x;
    const int wave = tid >> 6, lane = tid & 63;
    const int quad = lane >> 4, l16 = lane & 15;
    const int wr = (wave >> 1) * 64, wc = (wave & 1) * 64;
    const int srow = lane & 15, schunk = lane >> 4;

    floatx4 acc[4][4];
    for (int i = 0; i < 4; i++)
        for (int j = 0; j < 4; j++) acc[i][j] = (floatx4){0.f, 0.f, 0.f, 0.f};

    const bf16_t* aptr0 = A  + (size_t)(m0 + wave * 32 + srow) * 768 + schunk * 8;
    const bf16_t* bptr0 = Bw + (size_t)(n0 + wave * 32 + srow) * 768 + schunk * 8;
    const int abase = wave * 1024;

    uint4 ar0, ar1, br0, br1;
    auto issue = [&](int k0) {
        ar0 = *(const uint4*)(aptr0 + k0);
        ar1 = *(const uint4*)(aptr0 + k0 + 16 * 768);
        br0 = *(const uint4*)(bptr0 + k0);
        br1 = *(const uint4*)(bptr0 + k0 + 16 * 768);
    };
    issue(0);

    for (int it = 0; it < 24; ++it) {
        __syncthreads();
        *(uint4*)&As[abase + lane * 8]       = ar0;
        *(uint4*)&As[abase + 512 + lane * 8] = ar1;
        *(uint4*)&Bs[abase + lane * 8]       = br0;
        *(uint4*)&Bs[abase + 512 + lane * 8] = br1;
        if (it < 23) issue((it + 1) * 32);
        __syncthreads();

        bf16x8 af[4], bfr[4];
#pragma unroll
        for (int i = 0; i < 4; i++)
            af[i] = *(const bf16x8*)&As[((wr >> 4) + i) * 512 + quad * 128 + l16 * 8];
#pragma unroll
        for (int j = 0; j < 4; j++)
            bfr[j] = *(const bf16x8*)&Bs[((wc >> 4) + j) * 512 + quad * 128 + l16 * 8];
#pragma unroll
        for (int i = 0; i < 4; i++)
#pragma unroll
            for (int j = 0; j < 4; j++) acc[i][j] = MFMA16x16x32(af[i], bfr[j], acc[i][j]);
    }
    for (int i = 0; i < 4; i++)
        for (int j = 0; j < 4; j++) {
            int n = n0 + wc + j * 16 + l16;
            for (int r = 0; r < 4; r++) {
                int m = m0 + wr + i * 16 + quad * 4 + r;
                out[(size_t)m * 768 + n] = acc[i][j][r];
            }
        }
}

// ---------------------------------------------------------------------------
extern "C" void kernel_launch(void* const* d_in, const int* in_sizes, int n_in,
                              void* d_out, int out_size, void* d_ws, size_t ws_size,
                              hipStream_t stream) {
    const float* x     = (const float*)d_in[0];   // (4,2048,768)
    const float* qkv_w = (const float*)d_in[1];   // (2304,768)
    const float* out_w = (const float*)d_in[2];   // (768,768)
    float* out = (float*)d_out;

    char* ws = (char*)d_ws;
    bf16_t* wn_all = (bf16_t*)(ws + 0);          //  4,718,592  (3072x768 bf16: qkv_w rows then out_w rows)
    bf16_t* xb     = (bf16_t*)(ws + 4718592);    // 12,582,912  (8192x768 bf16)
    float*  mag    = (float*) (ws + 17301504);   //     32,768  (8192 fp32)
    bf16_t* qkvh   = (bf16_t*)(ws + 17334272);   // 25,165,824  (2x4x12x2048x64 bf16: q,k)
    bf16_t* vT     = (bf16_t*)(ws + 42500096);   // 12,582,912  (48x64x2048 bf16, plain transpose)
    bf16_t* y      = (bf16_t*)(ws + 55083008);   // 12,582,912  (8192x768 bf16)
    // total 67,665,920 bytes

    bf16_t* ow = wn_all + (size_t)2304 * 768;

    prep_kernel<<<11264, 256, 0, stream>>>(x, qkv_w, out_w, wn_all, xb, mag);
    gemm_qkv_kernel<<<dim3(64, 18), 256, 0, stream>>>(xb, wn_all, qkvh, vT);
    attn_kernel<<<dim3(48, 16), 512, 0, stream>>>(qkvh, vT, mag, y);
    gemm_out_kernel<<<dim3(64, 6), 256, 0, stream>>>(y, ow, out);
}